// Round 13
// baseline (312.460 us; speedup 1.0000x reference)
//
#include <hip/hip_runtime.h>

#define N_ENT   100000
#define N_USR   4096
#define N_ITEM  8192
#define N_REL   32
#define N_CLS   3
#define DD      128
#define N_EDGES 800000
#define NNZ     204800

#define CAP_E   64
#define CAP_U   128

typedef __attribute__((ext_vector_type(8))) short short8;
typedef __attribute__((ext_vector_type(4))) float f32x4;

static __device__ __forceinline__ unsigned short f2bf(float x) {
    unsigned int u = __builtin_bit_cast(unsigned int, x);
    u = (u + 0x7fffu + ((u >> 16) & 1u)) >> 16;
    return (unsigned short)u;
}
static __device__ __forceinline__ float bflo(unsigned int v) {
    return __uint_as_float(v << 16);
}
static __device__ __forceinline__ float bfhi(unsigned int v) {
    return __uint_as_float(v & 0xffff0000u);
}

// ---------------- node 1: light prep {zero cnt | item2 -> Bt | uatt} -------
#define ZB  ((N_ENT + N_USR + 255) / 256)   // 407

__global__ __launch_bounds__(256) void k_prep_light(const float* __restrict__ rel,
                                                    int* __restrict__ cnt,
                                                    const float* __restrict__ item,
                                                    unsigned short* __restrict__ Bt,
                                                    const float* __restrict__ usr,
                                                    const float* __restrict__ w,
                                                    float* __restrict__ uatt) {
    __shared__ float smem[32 * 33 + 32];
    int bx = blockIdx.x;

    if (bx < ZB) {                          // ---- zero cnt ----
        int i = bx * 256 + threadIdx.x;
        if (i < N_ENT + N_USR) cnt[i] = 0;
        return;
    }
    bx -= ZB;

    if (bx < 1024) {                        // ---- item2 tiled transpose -> Bt ----
        float (*tile)[33] = (float(*)[33])smem;
        float* ssum = smem + 32 * 33;
        const int b2 = bx & 255, by = bx >> 8;
        const int tx = threadIdx.x & 31, ty = threadIdx.x >> 5;
        const int i0 = b2 * 32, d0 = by * 32;
        if (threadIdx.x < 32) {
            float s = 0.f;
            for (int r = 0; r < N_REL; ++r) s += rel[r * DD + d0 + threadIdx.x];
            ssum[threadIdx.x] = s;
        }
#pragma unroll
        for (int rr = 0; rr < 4; ++rr)
            tile[ty + 8 * rr][tx] = item[(size_t)(i0 + ty + 8 * rr) * DD + d0 + tx];
        __syncthreads();
#pragma unroll
        for (int rr = 0; rr < 4; ++rr) {
            int d = d0 + ty + 8 * rr;
            Bt[(size_t)d * N_ITEM + i0 + tx] = f2bf(tile[tx][ty + 8 * rr] * ssum[ty + 8 * rr]);
        }
        return;
    }
    bx -= 1024;

    {                                       // ---- user_cls_att (16 blocks) ----
        for (int i = threadIdx.x; i < N_CLS * DD; i += 256) smem[i] = w[i];
        __syncthreads();
        int u = bx * 256 + threadIdx.x;
        const float4* row = (const float4*)(usr + (size_t)u * DD);
        float acc[3] = {0.f, 0.f, 0.f};
        for (int dq = 0; dq < DD / 4; ++dq) {
            float4 v = row[dq];
#pragma unroll
            for (int c = 0; c < 3; ++c) {
                float4 ww = *(const float4*)&smem[c * DD + dq * 4];
                acc[c] += v.x * ww.x + v.y * ww.y + v.z * ww.z + v.w * ww.w;
            }
        }
        float m = fmaxf(acc[0], fmaxf(acc[1], acc[2]));
        float s = 0.f;
#pragma unroll
        for (int c = 0; c < 3; ++c) { acc[c] = __expf(acc[c] - m); s += acc[c]; }
        float inv = 1.f / s;
#pragma unroll
        for (int c = 0; c < 3; ++c) uatt[u * 3 + c] = acc[c] * inv;
    }
}

// ---------------- node 2: {ent_att || bucket scatter} (both low-VGPR) ------
#define EAB ((N_ENT + 255) / 256)             // 391
#define SCAT_BLOCKS ((N_EDGES + 255) / 256)   // 3125

__global__ __launch_bounds__(256) void k_att_scatter(const float* __restrict__ ent,
                                                     const float* __restrict__ rel,
                                                     float* __restrict__ att,
                                                     unsigned short* __restrict__ entbf,
                                                     unsigned short* __restrict__ relbf,
                                                     const int* __restrict__ eidx,
                                                     const int* __restrict__ etyp,
                                                     const float* __restrict__ eimp,
                                                     const int* __restrict__ irow,
                                                     const int* __restrict__ icol,
                                                     const float* __restrict__ ival,
                                                     int* __restrict__ cnt,
                                                     int2* __restrict__ pack_e,
                                                     int2* __restrict__ pack_u) {
    __shared__ float smemf[N_REL * DD];       // used by ent_att branch only

    if (blockIdx.x < EAB) {
        // ================= ent_att + bf16 tables ===========================
        int bx = blockIdx.x;
        for (int i = threadIdx.x; i < N_REL * DD; i += 256) smemf[i] = rel[i];
        __syncthreads();
        if (bx == 0) {
            for (int i = threadIdx.x; i < N_REL * DD; i += 256)
                relbf[i] = f2bf(smemf[i]);
        }
        int e = bx * 256 + threadIdx.x;
        if (e >= N_ENT) return;
        const float4* row = (const float4*)(ent + (size_t)e * DD);
        unsigned short* brow = entbf + (size_t)e * DD;
        float acc[N_REL];
#pragma unroll
        for (int r = 0; r < N_REL; ++r) acc[r] = 0.f;
        for (int dq = 0; dq < DD / 4; ++dq) {
            float4 v = row[dq];
            ushort4 bv;
            bv.x = f2bf(v.x); bv.y = f2bf(v.y); bv.z = f2bf(v.z); bv.w = f2bf(v.w);
            *(ushort4*)(brow + dq * 4) = bv;
#pragma unroll
            for (int r = 0; r < N_REL; ++r) {
                float4 ww = *(const float4*)&smemf[r * DD + dq * 4];
                acc[r] += v.x * ww.x + v.y * ww.y + v.z * ww.z + v.w * ww.w;
            }
        }
        float m = acc[0];
#pragma unroll
        for (int r = 1; r < N_REL; ++r) m = fmaxf(m, acc[r]);
        float s = 0.f;
#pragma unroll
        for (int r = 0; r < N_REL; ++r) { acc[r] = __expf(acc[r] - m); s += acc[r]; }
        float inv = 1.f / s;
        float* o = att + (size_t)e * N_REL;
#pragma unroll
        for (int r = 0; r < N_REL; ++r) o[r] = acc[r] * inv;
    } else {
        // ================= bucket scatter ==================================
        int i = (blockIdx.x - EAB) * 256 + threadIdx.x;
        if (i < N_EDGES) {
            int h = eidx[i], tl = eidx[N_EDGES + i], r = etyp[i];
            int p = atomicAdd(&cnt[h], 1);
            if (p < CAP_E) {
                int2 pk;
                pk.x = tl | (r << 24);
                pk.y = __float_as_int(eimp[i]);
                pack_e[(size_t)h * CAP_E + p] = pk;
            }
        }
        if (i < NNZ) {
            int u = irow[i];
            int p = atomicAdd(&cnt[N_ENT + u], 1);
            if (p < CAP_U) {
                int2 pk;
                pk.x = icol[i];
                pk.y = __float_as_int(ival[i]);
                pack_u[(size_t)u * CAP_U + p] = pk;
            }
        }
    }
}

// ---------------- node 3: dedicated disen GEMM (own regalloc) --------------
#define BM 64
#define BK 32
#define SPLITK 16
#define KCH (N_ITEM / SPLITK)                 // 512
#define PLANE ((long long)N_USR * N_ITEM)
#define GEMM_BLOCKS ((N_USR / BM) * SPLITK)   // 1024

__global__ __launch_bounds__(256) void k_disen_gemm(const float* __restrict__ icm,
                                                    const unsigned short* __restrict__ Bt,
                                                    const float* __restrict__ uatt,
                                                    float* __restrict__ part) {
    __shared__ unsigned short sA[BM][40];
    __shared__ unsigned short sB[DD][40];

    const int t  = threadIdx.x;
    const int m0 = blockIdx.x * BM;
    const long long k0b = (long long)blockIdx.y * KCH;

    const int ua = t >> 3;
    const int qa = t & 7;
    const float a00 = uatt[(m0 + ua) * 3 + 0];
    const float a01 = uatt[(m0 + ua) * 3 + 1];
    const float a02 = uatt[(m0 + ua) * 3 + 2];
    const float a10 = uatt[(m0 + ua + 32) * 3 + 0];
    const float a11 = uatt[(m0 + ua + 32) * 3 + 1];
    const float a12 = uatt[(m0 + ua + 32) * 3 + 2];

    const int db = t >> 2;
    const int qb = t & 3;

    const int lane = t & 63;
    const int wv = t >> 6;
    const int wm = wv >> 1, wn = wv & 1;
    const int la = lane & 15, lb = lane >> 4;

    f32x4 acc[2][4];
#pragma unroll
    for (int mi = 0; mi < 2; ++mi)
#pragma unroll
        for (int ni = 0; ni < 4; ++ni) {
            f32x4 z = {0.f, 0.f, 0.f, 0.f};
            acc[mi][ni] = z;
        }

    float4 rA0[3], rA1[3];
    short8 rB0, rB1;
    {
        const long long base0 = (long long)(m0 + ua) * N_ITEM + k0b + qa * 4;
        rA0[0] = *(const float4*)(icm + base0);
        rA0[1] = *(const float4*)(icm + base0 + PLANE);
        rA0[2] = *(const float4*)(icm + base0 + 2 * PLANE);
        const long long base1 = base0 + 32ll * N_ITEM;
        rA1[0] = *(const float4*)(icm + base1);
        rA1[1] = *(const float4*)(icm + base1 + PLANE);
        rA1[2] = *(const float4*)(icm + base1 + 2 * PLANE);
        const unsigned short* g0 = Bt + (long long)db * N_ITEM + k0b + qb * 8;
        rB0 = *(const short8*)g0;
        rB1 = *(const short8*)(g0 + 64ll * N_ITEM);
    }

    for (int kk = 0; kk < KCH; kk += BK) {
        __syncthreads();
        {
            ushort4 p;
            p.x = f2bf(a00 * rA0[0].x + a01 * rA0[1].x + a02 * rA0[2].x);
            p.y = f2bf(a00 * rA0[0].y + a01 * rA0[1].y + a02 * rA0[2].y);
            p.z = f2bf(a00 * rA0[0].z + a01 * rA0[1].z + a02 * rA0[2].z);
            p.w = f2bf(a00 * rA0[0].w + a01 * rA0[1].w + a02 * rA0[2].w);
            *(ushort4*)(&sA[ua][0] + qa * 4) = p;
            p.x = f2bf(a10 * rA1[0].x + a11 * rA1[1].x + a12 * rA1[2].x);
            p.y = f2bf(a10 * rA1[0].y + a11 * rA1[1].y + a12 * rA1[2].y);
            p.z = f2bf(a10 * rA1[0].z + a11 * rA1[1].z + a12 * rA1[2].z);
            p.w = f2bf(a10 * rA1[0].w + a11 * rA1[1].w + a12 * rA1[2].w);
            *(ushort4*)(&sA[ua + 32][0] + qa * 4) = p;
            *(short8*)(&sB[db][0] + qb * 8) = rB0;
            *(short8*)(&sB[db + 64][0] + qb * 8) = rB1;
        }
        __syncthreads();

        if (kk + BK < KCH) {
            const long long k0 = k0b + kk + BK;
            const long long base0 = (long long)(m0 + ua) * N_ITEM + k0 + qa * 4;
            rA0[0] = *(const float4*)(icm + base0);
            rA0[1] = *(const float4*)(icm + base0 + PLANE);
            rA0[2] = *(const float4*)(icm + base0 + 2 * PLANE);
            const long long base1 = base0 + 32ll * N_ITEM;
            rA1[0] = *(const float4*)(icm + base1);
            rA1[1] = *(const float4*)(icm + base1 + PLANE);
            rA1[2] = *(const float4*)(icm + base1 + 2 * PLANE);
            const unsigned short* g0 = Bt + (long long)db * N_ITEM + k0 + qb * 8;
            rB0 = *(const short8*)g0;
            rB1 = *(const short8*)(g0 + 64ll * N_ITEM);
        }

        short8 af[2], bfr[4];
#pragma unroll
        for (int mi = 0; mi < 2; ++mi)
            af[mi] = *(const short8*)(&sA[wm * 32 + mi * 16 + la][0] + lb * 8);
#pragma unroll
        for (int ni = 0; ni < 4; ++ni)
            bfr[ni] = *(const short8*)(&sB[wn * 64 + ni * 16 + la][0] + lb * 8);
#pragma unroll
        for (int mi = 0; mi < 2; ++mi)
#pragma unroll
            for (int ni = 0; ni < 4; ++ni)
                acc[mi][ni] = __builtin_amdgcn_mfma_f32_16x16x32_bf16(
                    af[mi], bfr[ni], acc[mi][ni], 0, 0, 0);
    }

    float* pbase = part + (size_t)blockIdx.y * ((size_t)N_USR * DD);
#pragma unroll
    for (int mi = 0; mi < 2; ++mi)
#pragma unroll
        for (int ni = 0; ni < 4; ++ni)
#pragma unroll
            for (int r = 0; r < 4; ++r) {
                int row = m0 + wm * 32 + mi * 16 + lb * 4 + r;
                int col = wn * 64 + ni * 16 + la;
                pbase[(size_t)row * DD + col] = acc[mi][ni][r];
            }
}

// ---------------- node 4: {edge agg (16-lane groups) || user gather} -------
#define EDGE_BLOCKS (N_ENT / 16)     // 6250
#define USER_BLOCKS (N_USR / 4)      // 1024

__global__ __launch_bounds__(256) void k_node3(const unsigned short* __restrict__ entbf,
                                               const unsigned short* __restrict__ relbf,
                                               const float* __restrict__ att,
                                               const int2* __restrict__ pack_e,
                                               const int2* __restrict__ pack_u,
                                               const int* __restrict__ cnt,
                                               const float* __restrict__ part,
                                               float* __restrict__ out_ent,
                                               float* __restrict__ out_usr) {
    const int lane = threadIdx.x & 63;

    if (blockIdx.x < EDGE_BLOCKS) {
        const int wid = blockIdx.x * 4 + (threadIdx.x >> 6);
        const int l15 = lane & 15;
        const int grp = lane >> 4;           // 0..3
#pragma unroll 1
        for (int hh = 0; hh < 4; ++hh) {
            const int h = wid * 4 + hh;
            const int n = min(cnt[h], CAP_E);
            const float attv = att[(size_t)h * N_REL + (lane & 31)];
            const int2* seg = pack_e + (size_t)h * CAP_E;
            float acc[8];
#pragma unroll
            for (int e = 0; e < 8; ++e) acc[e] = 0.f;
            for (int j = 0; j < n; j += 8) {
                const int e0 = j + grp, e1 = j + 4 + grp;
                int2 p0 = seg[min(e0, n - 1)];
                int2 p1 = seg[min(e1, n - 1)];
                const int r0 = ((unsigned)p0.x) >> 24;
                const int r1 = ((unsigned)p1.x) >> 24;
                float s0 = __shfl(attv, r0, 64) * __int_as_float(p0.y);
                float s1 = __shfl(attv, r1, 64) * __int_as_float(p1.y);
                s0 = (e0 < n) ? s0 : 0.f;
                s1 = (e1 < n) ? s1 : 0.f;
                uint4 b0 = ((const uint4*)(entbf + (size_t)(p0.x & 0xFFFFFF) * DD))[l15];
                uint4 b1 = ((const uint4*)(entbf + (size_t)(p1.x & 0xFFFFFF) * DD))[l15];
                uint4 v0 = ((const uint4*)(relbf + (size_t)r0 * DD))[l15];
                uint4 v1 = ((const uint4*)(relbf + (size_t)r1 * DD))[l15];
                const unsigned* bp0 = (const unsigned*)&b0;
                const unsigned* bp1 = (const unsigned*)&b1;
                const unsigned* vp0 = (const unsigned*)&v0;
                const unsigned* vp1 = (const unsigned*)&v1;
#pragma unroll
                for (int q = 0; q < 4; ++q) {
                    acc[2 * q]     = fmaf(bflo(bp0[q]) * bflo(vp0[q]), s0, acc[2 * q]);
                    acc[2 * q + 1] = fmaf(bfhi(bp0[q]) * bfhi(vp0[q]), s0, acc[2 * q + 1]);
                    acc[2 * q]     = fmaf(bflo(bp1[q]) * bflo(vp1[q]), s1, acc[2 * q]);
                    acc[2 * q + 1] = fmaf(bfhi(bp1[q]) * bfhi(vp1[q]), s1, acc[2 * q + 1]);
                }
            }
#pragma unroll
            for (int e = 0; e < 8; ++e) {
                acc[e] += __shfl_xor(acc[e], 16, 64);
                acc[e] += __shfl_xor(acc[e], 32, 64);
            }
            if (lane < 16) {
                float4 o0 = {acc[0], acc[1], acc[2], acc[3]};
                float4 o1 = {acc[4], acc[5], acc[6], acc[7]};
                float4* dst = (float4*)(out_ent + (size_t)h * DD) + l15 * 2;
                dst[0] = o0;
                dst[1] = o1;
            }
        }
    } else {
        const int u = (blockIdx.x - EDGE_BLOCKS) * 4 + (threadIdx.x >> 6);
        const int n = min(cnt[N_ENT + u], CAP_U);
        const int2* seg = pack_u + (size_t)u * CAP_U;
        float ax = 0.f, ay = 0.f;
        for (int j = 0; j < n; j += 8) {
            int2 pk[8];
#pragma unroll
            for (int k = 0; k < 8; ++k) pk[k] = seg[min(j + k, n - 1)];
            unsigned int bv[8];
            float sc[8];
#pragma unroll
            for (int k = 0; k < 8; ++k) {
                sc[k] = (j + k < n) ? __int_as_float(pk[k].y) : 0.f;
                bv[k] = ((const unsigned int*)(entbf + (size_t)pk[k].x * DD))[lane];
            }
#pragma unroll
            for (int k = 0; k < 8; ++k) {
                ax = fmaf(bflo(bv[k]), sc[k], ax);
                ay = fmaf(bfhi(bv[k]), sc[k], ay);
            }
        }
#pragma unroll
        for (int k = 0; k < SPLITK; ++k) {
            float2 p = ((const float2*)(part + (size_t)k * N_USR * DD + (size_t)u * DD))[lane];
            ax += p.x;
            ay += p.y;
        }
        float2 o; o.x = ax; o.y = ay;
        ((float2*)(out_usr + (size_t)u * DD))[lane] = o;
    }
}

// ---------------------------------------------------------------------------
static constexpr size_t algn(size_t x) { return (x + 255) & ~(size_t)255; }

extern "C" void kernel_launch(void* const* d_in, const int* in_sizes, int n_in,
                              void* d_out, int out_size, void* d_ws, size_t ws_size,
                              hipStream_t stream) {
    const float* ent  = (const float*)d_in[0];
    const float* item = (const float*)d_in[1];
    const float* usr  = (const float*)d_in[2];
    const float* rel  = (const float*)d_in[4];
    const int*   eidx = (const int*)d_in[5];
    const int*   etyp = (const int*)d_in[6];
    const float* eimp = (const float*)d_in[7];
    const int*   irow = (const int*)d_in[8];
    const int*   icol = (const int*)d_in[9];
    const float* ival = (const float*)d_in[10];
    const float* uclw = (const float*)d_in[13];
    const float* icm  = (const float*)d_in[14];

    float* out_ent = (float*)d_out;
    float* out_usr = out_ent + (size_t)N_ENT * DD;

    char* w = (char*)d_ws;
    size_t o = 0;
    float* ws_att  = (float*)(w + o);  o = algn(o + (size_t)N_ENT * N_REL * 4);
    float* ws_uatt = (float*)(w + o);  o = algn(o + (size_t)N_USR * N_CLS * 4);
    unsigned short* ws_Bt    = (unsigned short*)(w + o); o = algn(o + (size_t)DD * N_ITEM * 2);
    unsigned short* ws_entbf = (unsigned short*)(w + o); o = algn(o + (size_t)N_ENT * DD * 2);
    unsigned short* ws_relbf = (unsigned short*)(w + o); o = algn(o + (size_t)N_REL * DD * 2);
    int*  ws_cnt   = (int*)(w + o);  o = algn(o + (size_t)(N_ENT + N_USR) * 4);
    int2* pack_e   = (int2*)(w + o); o = algn(o + (size_t)N_ENT * CAP_E * 8);
    int2* pack_u   = (int2*)(w + o); o = algn(o + (size_t)N_USR * CAP_U * 8);
    float* part    = (float*)(w + o); o = algn(o + (size_t)SPLITK * N_USR * DD * 4);

    (void)in_sizes; (void)n_in; (void)ws_size; (void)out_size;

    // 4 nodes: prep_light -> {ent_att || scatter} -> gemm -> {edge || user}
    k_prep_light<<<ZB + 1024 + 16, 256, 0, stream>>>(rel, ws_cnt, item, ws_Bt,
                                                     usr, uclw, ws_uatt);
    k_att_scatter<<<EAB + SCAT_BLOCKS, 256, 0, stream>>>(ent, rel, ws_att, ws_entbf,
                                                         ws_relbf, eidx, etyp, eimp,
                                                         irow, icol, ival, ws_cnt,
                                                         pack_e, pack_u);
    k_disen_gemm<<<dim3(N_USR / BM, SPLITK), 256, 0, stream>>>(icm, ws_Bt, ws_uatt, part);
    k_node3<<<EDGE_BLOCKS + USER_BLOCKS, 256, 0, stream>>>(ws_entbf, ws_relbf, ws_att,
                                                           pack_e, pack_u, ws_cnt, part,
                                                           out_ent, out_usr);
}

// Round 14
// 284.808 us; speedup vs baseline: 1.0971x; 1.0971x over previous
//
#include <hip/hip_runtime.h>

#define N_ENT   100000
#define N_USR   4096
#define N_ITEM  8192
#define N_REL   32
#define N_CLS   3
#define DD      128
#define N_EDGES 800000
#define NNZ     204800

#define CAP_E   64
#define CAP_U   128

typedef __attribute__((ext_vector_type(8))) short short8;
typedef __attribute__((ext_vector_type(4))) float f32x4;

static __device__ __forceinline__ unsigned short f2bf(float x) {
    unsigned int u = __builtin_bit_cast(unsigned int, x);
    u = (u + 0x7fffu + ((u >> 16) & 1u)) >> 16;
    return (unsigned short)u;
}
static __device__ __forceinline__ float bflo(unsigned int v) {
    return __uint_as_float(v << 16);
}
static __device__ __forceinline__ float bfhi(unsigned int v) {
    return __uint_as_float(v & 0xffff0000u);
}

// ---------------- node 1: light prep {zero cnt | item2 -> Bt | uatt} -------
#define ZB  ((N_ENT + N_USR + 255) / 256)   // 407

__global__ __launch_bounds__(256) void k_prep_light(const float* __restrict__ rel,
                                                    int* __restrict__ cnt,
                                                    const float* __restrict__ item,
                                                    unsigned short* __restrict__ Bt,
                                                    const float* __restrict__ usr,
                                                    const float* __restrict__ w,
                                                    float* __restrict__ uatt) {
    __shared__ float smem[32 * 33 + 32];
    int bx = blockIdx.x;

    if (bx < ZB) {                          // ---- zero cnt ----
        int i = bx * 256 + threadIdx.x;
        if (i < N_ENT + N_USR) cnt[i] = 0;
        return;
    }
    bx -= ZB;

    if (bx < 1024) {                        // ---- item2 tiled transpose -> Bt ----
        float (*tile)[33] = (float(*)[33])smem;
        float* ssum = smem + 32 * 33;
        const int b2 = bx & 255, by = bx >> 8;
        const int tx = threadIdx.x & 31, ty = threadIdx.x >> 5;
        const int i0 = b2 * 32, d0 = by * 32;
        if (threadIdx.x < 32) {
            float s = 0.f;
            for (int r = 0; r < N_REL; ++r) s += rel[r * DD + d0 + threadIdx.x];
            ssum[threadIdx.x] = s;
        }
#pragma unroll
        for (int rr = 0; rr < 4; ++rr)
            tile[ty + 8 * rr][tx] = item[(size_t)(i0 + ty + 8 * rr) * DD + d0 + tx];
        __syncthreads();
#pragma unroll
        for (int rr = 0; rr < 4; ++rr) {
            int d = d0 + ty + 8 * rr;
            Bt[(size_t)d * N_ITEM + i0 + tx] = f2bf(tile[tx][ty + 8 * rr] * ssum[ty + 8 * rr]);
        }
        return;
    }
    bx -= 1024;

    {                                       // ---- user_cls_att (16 blocks) ----
        for (int i = threadIdx.x; i < N_CLS * DD; i += 256) smem[i] = w[i];
        __syncthreads();
        int u = bx * 256 + threadIdx.x;
        const float4* row = (const float4*)(usr + (size_t)u * DD);
        float acc[3] = {0.f, 0.f, 0.f};
        for (int dq = 0; dq < DD / 4; ++dq) {
            float4 v = row[dq];
#pragma unroll
            for (int c = 0; c < 3; ++c) {
                float4 ww = *(const float4*)&smem[c * DD + dq * 4];
                acc[c] += v.x * ww.x + v.y * ww.y + v.z * ww.z + v.w * ww.w;
            }
        }
        float m = fmaxf(acc[0], fmaxf(acc[1], acc[2]));
        float s = 0.f;
#pragma unroll
        for (int c = 0; c < 3; ++c) { acc[c] = __expf(acc[c] - m); s += acc[c]; }
        float inv = 1.f / s;
#pragma unroll
        for (int c = 0; c < 3; ++c) uatt[u * 3 + c] = acc[c] * inv;
    }
}

// ---------------- node 2: {disen GEMM || ent_att || bucket scatter} --------
// __launch_bounds__(256, 1): r12's merged kernel was throttled to VGPR=64 by
// the occupancy heuristic (optimizing for the 3516 trivial blocks), forcing
// ~125MB of scratch spill in the gemm branch (WRITE_SIZE 215MB vs ~90 legit).
// min-waves/EU=1 lifts the cap so the gemm branch gets its ~120 VGPRs.
#define BM 64
#define BK 32
#define SPLITK 16
#define KCH (N_ITEM / SPLITK)                 // 512
#define PLANE ((long long)N_USR * N_ITEM)
#define GEMM_BLOCKS ((N_USR / BM) * SPLITK)   // 1024
#define EAB ((N_ENT + 255) / 256)             // 391
#define SCAT_BLOCKS ((N_EDGES + 255) / 256)   // 3125

__global__ __launch_bounds__(256, 1) void k_node2(const float* __restrict__ icm,
                                                  const unsigned short* __restrict__ Bt,
                                                  const float* __restrict__ uatt,
                                                  float* __restrict__ part,
                                                  const float* __restrict__ ent,
                                                  const float* __restrict__ rel,
                                                  float* __restrict__ att,
                                                  unsigned short* __restrict__ entbf,
                                                  unsigned short* __restrict__ relbf,
                                                  const int* __restrict__ eidx,
                                                  const int* __restrict__ etyp,
                                                  const float* __restrict__ eimp,
                                                  const int* __restrict__ irow,
                                                  const int* __restrict__ icol,
                                                  const float* __restrict__ ival,
                                                  int* __restrict__ cnt,
                                                  int2* __restrict__ pack_e,
                                                  int2* __restrict__ pack_u) {
    __shared__ float smemf[N_REL * DD];       // 16 KB union

    if (blockIdx.x < GEMM_BLOCKS) {
        // ================= GEMM branch =====================================
        unsigned short* smem = (unsigned short*)smemf;
        unsigned short (*sA)[40] = (unsigned short(*)[40])smem;
        unsigned short (*sB)[40] = (unsigned short(*)[40])(smem + BM * 40);

        const int t  = threadIdx.x;
        const int m0 = (blockIdx.x & 63) * BM;
        const int ky = blockIdx.x >> 6;
        const long long k0b = (long long)ky * KCH;

        const int ua = t >> 3;
        const int qa = t & 7;
        const float a00 = uatt[(m0 + ua) * 3 + 0];
        const float a01 = uatt[(m0 + ua) * 3 + 1];
        const float a02 = uatt[(m0 + ua) * 3 + 2];
        const float a10 = uatt[(m0 + ua + 32) * 3 + 0];
        const float a11 = uatt[(m0 + ua + 32) * 3 + 1];
        const float a12 = uatt[(m0 + ua + 32) * 3 + 2];

        const int db = t >> 2;
        const int qb = t & 3;

        const int lane = t & 63;
        const int wv = t >> 6;
        const int wm = wv >> 1, wn = wv & 1;
        const int la = lane & 15, lb = lane >> 4;

        f32x4 acc[2][4];
#pragma unroll
        for (int mi = 0; mi < 2; ++mi)
#pragma unroll
            for (int ni = 0; ni < 4; ++ni) {
                f32x4 z = {0.f, 0.f, 0.f, 0.f};
                acc[mi][ni] = z;
            }

        float4 rA0[3], rA1[3];
        short8 rB0, rB1;
        {
            const long long base0 = (long long)(m0 + ua) * N_ITEM + k0b + qa * 4;
            rA0[0] = *(const float4*)(icm + base0);
            rA0[1] = *(const float4*)(icm + base0 + PLANE);
            rA0[2] = *(const float4*)(icm + base0 + 2 * PLANE);
            const long long base1 = base0 + 32ll * N_ITEM;
            rA1[0] = *(const float4*)(icm + base1);
            rA1[1] = *(const float4*)(icm + base1 + PLANE);
            rA1[2] = *(const float4*)(icm + base1 + 2 * PLANE);
            const unsigned short* g0 = Bt + (long long)db * N_ITEM + k0b + qb * 8;
            rB0 = *(const short8*)g0;
            rB1 = *(const short8*)(g0 + 64ll * N_ITEM);
        }

        for (int kk = 0; kk < KCH; kk += BK) {
            __syncthreads();
            {
                ushort4 p;
                p.x = f2bf(a00 * rA0[0].x + a01 * rA0[1].x + a02 * rA0[2].x);
                p.y = f2bf(a00 * rA0[0].y + a01 * rA0[1].y + a02 * rA0[2].y);
                p.z = f2bf(a00 * rA0[0].z + a01 * rA0[1].z + a02 * rA0[2].z);
                p.w = f2bf(a00 * rA0[0].w + a01 * rA0[1].w + a02 * rA0[2].w);
                *(ushort4*)(&sA[ua][0] + qa * 4) = p;
                p.x = f2bf(a10 * rA1[0].x + a11 * rA1[1].x + a12 * rA1[2].x);
                p.y = f2bf(a10 * rA1[0].y + a11 * rA1[1].y + a12 * rA1[2].y);
                p.z = f2bf(a10 * rA1[0].z + a11 * rA1[1].z + a12 * rA1[2].z);
                p.w = f2bf(a10 * rA1[0].w + a11 * rA1[1].w + a12 * rA1[2].w);
                *(ushort4*)(&sA[ua + 32][0] + qa * 4) = p;
                *(short8*)(&sB[db][0] + qb * 8) = rB0;
                *(short8*)(&sB[db + 64][0] + qb * 8) = rB1;
            }
            __syncthreads();

            if (kk + BK < KCH) {
                const long long k0 = k0b + kk + BK;
                const long long base0 = (long long)(m0 + ua) * N_ITEM + k0 + qa * 4;
                rA0[0] = *(const float4*)(icm + base0);
                rA0[1] = *(const float4*)(icm + base0 + PLANE);
                rA0[2] = *(const float4*)(icm + base0 + 2 * PLANE);
                const long long base1 = base0 + 32ll * N_ITEM;
                rA1[0] = *(const float4*)(icm + base1);
                rA1[1] = *(const float4*)(icm + base1 + PLANE);
                rA1[2] = *(const float4*)(icm + base1 + 2 * PLANE);
                const unsigned short* g0 = Bt + (long long)db * N_ITEM + k0 + qb * 8;
                rB0 = *(const short8*)g0;
                rB1 = *(const short8*)(g0 + 64ll * N_ITEM);
            }

            short8 af[2], bfr[4];
#pragma unroll
            for (int mi = 0; mi < 2; ++mi)
                af[mi] = *(const short8*)(&sA[wm * 32 + mi * 16 + la][0] + lb * 8);
#pragma unroll
            for (int ni = 0; ni < 4; ++ni)
                bfr[ni] = *(const short8*)(&sB[wn * 64 + ni * 16 + la][0] + lb * 8);
#pragma unroll
            for (int mi = 0; mi < 2; ++mi)
#pragma unroll
                for (int ni = 0; ni < 4; ++ni)
                    acc[mi][ni] = __builtin_amdgcn_mfma_f32_16x16x32_bf16(
                        af[mi], bfr[ni], acc[mi][ni], 0, 0, 0);
        }

        float* pbase = part + (size_t)ky * ((size_t)N_USR * DD);
#pragma unroll
        for (int mi = 0; mi < 2; ++mi)
#pragma unroll
            for (int ni = 0; ni < 4; ++ni)
#pragma unroll
                for (int r = 0; r < 4; ++r) {
                    int row = m0 + wm * 32 + mi * 16 + lb * 4 + r;
                    int col = wn * 64 + ni * 16 + la;
                    pbase[(size_t)row * DD + col] = acc[mi][ni][r];
                }
        return;
    }

    if (blockIdx.x < GEMM_BLOCKS + EAB) {
        // ================= ent_att + bf16 tables (overlaps gemm tail) ======
        int bx = blockIdx.x - GEMM_BLOCKS;
        for (int i = threadIdx.x; i < N_REL * DD; i += 256) smemf[i] = rel[i];
        __syncthreads();
        if (bx == 0) {
            for (int i = threadIdx.x; i < N_REL * DD; i += 256)
                relbf[i] = f2bf(smemf[i]);
        }
        int e = bx * 256 + threadIdx.x;
        if (e >= N_ENT) return;
        const float4* row = (const float4*)(ent + (size_t)e * DD);
        unsigned short* brow = entbf + (size_t)e * DD;
        float acc[N_REL];
#pragma unroll
        for (int r = 0; r < N_REL; ++r) acc[r] = 0.f;
        for (int dq = 0; dq < DD / 4; ++dq) {
            float4 v = row[dq];
            ushort4 bv;
            bv.x = f2bf(v.x); bv.y = f2bf(v.y); bv.z = f2bf(v.z); bv.w = f2bf(v.w);
            *(ushort4*)(brow + dq * 4) = bv;
#pragma unroll
            for (int r = 0; r < N_REL; ++r) {
                float4 ww = *(const float4*)&smemf[r * DD + dq * 4];
                acc[r] += v.x * ww.x + v.y * ww.y + v.z * ww.z + v.w * ww.w;
            }
        }
        float m = acc[0];
#pragma unroll
        for (int r = 1; r < N_REL; ++r) m = fmaxf(m, acc[r]);
        float s = 0.f;
#pragma unroll
        for (int r = 0; r < N_REL; ++r) { acc[r] = __expf(acc[r] - m); s += acc[r]; }
        float inv = 1.f / s;
        float* o = att + (size_t)e * N_REL;
#pragma unroll
        for (int r = 0; r < N_REL; ++r) o[r] = acc[r] * inv;
        return;
    }

    {
        // ================= bucket scatter ==================================
        int i = (blockIdx.x - GEMM_BLOCKS - EAB) * 256 + threadIdx.x;
        if (i < N_EDGES) {
            int h = eidx[i], tl = eidx[N_EDGES + i], r = etyp[i];
            int p = atomicAdd(&cnt[h], 1);
            if (p < CAP_E) {
                int2 pk;
                pk.x = tl | (r << 24);
                pk.y = __float_as_int(eimp[i]);
                pack_e[(size_t)h * CAP_E + p] = pk;
            }
        }
        if (i < NNZ) {
            int u = irow[i];
            int p = atomicAdd(&cnt[N_ENT + u], 1);
            if (p < CAP_U) {
                int2 pk;
                pk.x = icol[i];
                pk.y = __float_as_int(ival[i]);
                pack_u[(size_t)u * CAP_U + p] = pk;
            }
        }
    }
}

// ---------------- node 3: {edge agg (16-lane groups) || user gather} -------
#define EDGE_BLOCKS (N_ENT / 16)     // 6250
#define USER_BLOCKS (N_USR / 4)      // 1024

__global__ __launch_bounds__(256) void k_node3(const unsigned short* __restrict__ entbf,
                                               const unsigned short* __restrict__ relbf,
                                               const float* __restrict__ att,
                                               const int2* __restrict__ pack_e,
                                               const int2* __restrict__ pack_u,
                                               const int* __restrict__ cnt,
                                               const float* __restrict__ part,
                                               float* __restrict__ out_ent,
                                               float* __restrict__ out_usr) {
    const int lane = threadIdx.x & 63;

    if (blockIdx.x < EDGE_BLOCKS) {
        const int wid = blockIdx.x * 4 + (threadIdx.x >> 6);
        const int l15 = lane & 15;
        const int grp = lane >> 4;           // 0..3
#pragma unroll 1
        for (int hh = 0; hh < 4; ++hh) {
            const int h = wid * 4 + hh;
            const int n = min(cnt[h], CAP_E);
            const float attv = att[(size_t)h * N_REL + (lane & 31)];
            const int2* seg = pack_e + (size_t)h * CAP_E;
            float acc[8];
#pragma unroll
            for (int e = 0; e < 8; ++e) acc[e] = 0.f;
            for (int j = 0; j < n; j += 8) {
                const int e0 = j + grp, e1 = j + 4 + grp;
                int2 p0 = seg[min(e0, n - 1)];
                int2 p1 = seg[min(e1, n - 1)];
                const int r0 = ((unsigned)p0.x) >> 24;
                const int r1 = ((unsigned)p1.x) >> 24;
                float s0 = __shfl(attv, r0, 64) * __int_as_float(p0.y);
                float s1 = __shfl(attv, r1, 64) * __int_as_float(p1.y);
                s0 = (e0 < n) ? s0 : 0.f;
                s1 = (e1 < n) ? s1 : 0.f;
                uint4 b0 = ((const uint4*)(entbf + (size_t)(p0.x & 0xFFFFFF) * DD))[l15];
                uint4 b1 = ((const uint4*)(entbf + (size_t)(p1.x & 0xFFFFFF) * DD))[l15];
                uint4 v0 = ((const uint4*)(relbf + (size_t)r0 * DD))[l15];
                uint4 v1 = ((const uint4*)(relbf + (size_t)r1 * DD))[l15];
                const unsigned* bp0 = (const unsigned*)&b0;
                const unsigned* bp1 = (const unsigned*)&b1;
                const unsigned* vp0 = (const unsigned*)&v0;
                const unsigned* vp1 = (const unsigned*)&v1;
#pragma unroll
                for (int q = 0; q < 4; ++q) {
                    acc[2 * q]     = fmaf(bflo(bp0[q]) * bflo(vp0[q]), s0, acc[2 * q]);
                    acc[2 * q + 1] = fmaf(bfhi(bp0[q]) * bfhi(vp0[q]), s0, acc[2 * q + 1]);
                    acc[2 * q]     = fmaf(bflo(bp1[q]) * bflo(vp1[q]), s1, acc[2 * q]);
                    acc[2 * q + 1] = fmaf(bfhi(bp1[q]) * bfhi(vp1[q]), s1, acc[2 * q + 1]);
                }
            }
#pragma unroll
            for (int e = 0; e < 8; ++e) {
                acc[e] += __shfl_xor(acc[e], 16, 64);
                acc[e] += __shfl_xor(acc[e], 32, 64);
            }
            if (lane < 16) {
                float4 o0 = {acc[0], acc[1], acc[2], acc[3]};
                float4 o1 = {acc[4], acc[5], acc[6], acc[7]};
                float4* dst = (float4*)(out_ent + (size_t)h * DD) + l15 * 2;
                dst[0] = o0;
                dst[1] = o1;
            }
        }
    } else {
        const int u = (blockIdx.x - EDGE_BLOCKS) * 4 + (threadIdx.x >> 6);
        const int n = min(cnt[N_ENT + u], CAP_U);
        const int2* seg = pack_u + (size_t)u * CAP_U;
        float ax = 0.f, ay = 0.f;
        for (int j = 0; j < n; j += 8) {
            int2 pk[8];
#pragma unroll
            for (int k = 0; k < 8; ++k) pk[k] = seg[min(j + k, n - 1)];
            unsigned int bv[8];
            float sc[8];
#pragma unroll
            for (int k = 0; k < 8; ++k) {
                sc[k] = (j + k < n) ? __int_as_float(pk[k].y) : 0.f;
                bv[k] = ((const unsigned int*)(entbf + (size_t)pk[k].x * DD))[lane];
            }
#pragma unroll
            for (int k = 0; k < 8; ++k) {
                ax = fmaf(bflo(bv[k]), sc[k], ax);
                ay = fmaf(bfhi(bv[k]), sc[k], ay);
            }
        }
#pragma unroll
        for (int k = 0; k < SPLITK; ++k) {
            float2 p = ((const float2*)(part + (size_t)k * N_USR * DD + (size_t)u * DD))[lane];
            ax += p.x;
            ay += p.y;
        }
        float2 o; o.x = ax; o.y = ay;
        ((float2*)(out_usr + (size_t)u * DD))[lane] = o;
    }
}

// ---------------------------------------------------------------------------
static constexpr size_t algn(size_t x) { return (x + 255) & ~(size_t)255; }

extern "C" void kernel_launch(void* const* d_in, const int* in_sizes, int n_in,
                              void* d_out, int out_size, void* d_ws, size_t ws_size,
                              hipStream_t stream) {
    const float* ent  = (const float*)d_in[0];
    const float* item = (const float*)d_in[1];
    const float* usr  = (const float*)d_in[2];
    const float* rel  = (const float*)d_in[4];
    const int*   eidx = (const int*)d_in[5];
    const int*   etyp = (const int*)d_in[6];
    const float* eimp = (const float*)d_in[7];
    const int*   irow = (const int*)d_in[8];
    const int*   icol = (const int*)d_in[9];
    const float* ival = (const float*)d_in[10];
    const float* uclw = (const float*)d_in[13];
    const float* icm  = (const float*)d_in[14];

    float* out_ent = (float*)d_out;
    float* out_usr = out_ent + (size_t)N_ENT * DD;

    char* w = (char*)d_ws;
    size_t o = 0;
    float* ws_att  = (float*)(w + o);  o = algn(o + (size_t)N_ENT * N_REL * 4);
    float* ws_uatt = (float*)(w + o);  o = algn(o + (size_t)N_USR * N_CLS * 4);
    unsigned short* ws_Bt    = (unsigned short*)(w + o); o = algn(o + (size_t)DD * N_ITEM * 2);
    unsigned short* ws_entbf = (unsigned short*)(w + o); o = algn(o + (size_t)N_ENT * DD * 2);
    unsigned short* ws_relbf = (unsigned short*)(w + o); o = algn(o + (size_t)N_REL * DD * 2);
    int*  ws_cnt   = (int*)(w + o);  o = algn(o + (size_t)(N_ENT + N_USR) * 4);
    int2* pack_e   = (int2*)(w + o); o = algn(o + (size_t)N_ENT * CAP_E * 8);
    int2* pack_u   = (int2*)(w + o); o = algn(o + (size_t)N_USR * CAP_U * 8);
    float* part    = (float*)(w + o); o = algn(o + (size_t)SPLITK * N_USR * DD * 4);

    (void)in_sizes; (void)n_in; (void)ws_size; (void)out_size;

    // 3 nodes: prep_light -> {gemm || ent_att || scatter} -> {edge || user}
    k_prep_light<<<ZB + 1024 + 16, 256, 0, stream>>>(rel, ws_cnt, item, ws_Bt,
                                                     usr, uclw, ws_uatt);
    k_node2<<<GEMM_BLOCKS + EAB + SCAT_BLOCKS, 256, 0, stream>>>(
        icm, ws_Bt, ws_uatt, part, ent, rel, ws_att, ws_entbf, ws_relbf,
        eidx, etyp, eimp, irow, icol, ival, ws_cnt, pack_e, pack_u);
    k_node3<<<EDGE_BLOCKS + USER_BLOCKS, 256, 0, stream>>>(ws_entbf, ws_relbf, ws_att,
                                                           pack_e, pack_u, ws_cnt, part,
                                                           out_ent, out_usr);
}